// Round 6
// baseline (13555.214 us; speedup 1.0000x reference)
//
#include <hip/hip_runtime.h>
#include <hip/hip_bf16.h>

#define SEQ   512
#define BATCH 128
#define VOCAB 30000
#define EDIM  256
#define HDIM  256
#define G4    1024   // 4*H
#define NT    9

// ---------------- K0b: detect mask storage dtype ----------------
__global__ void k_detect(const unsigned char* __restrict__ m, int* __restrict__ flag) {
    __shared__ int ok_sh;
    if (threadIdx.x == 0) ok_sh = 1;
    __syncthreads();
    int b = threadIdx.x;  // 128 threads, one row each
    const uint4* row = (const uint4*)(m + b * SEQ);
    int ok = 1, prev = 1;
    for (int i = 0; i < SEQ / 16; ++i) {
        uint4 v = row[i];
        unsigned w[4] = {v.x, v.y, v.z, v.w};
        #pragma unroll
        for (int wi = 0; wi < 4; ++wi) {
            #pragma unroll
            for (int j = 0; j < 4; ++j) {
                int byte = (w[wi] >> (8 * j)) & 255;
                if (byte > 1 || byte > prev) ok = 0;
                prev = byte;
            }
        }
    }
    if (!ok) atomicAnd(&ok_sh, 0);
    __syncthreads();
    if (threadIdx.x == 0) *flag = ok_sh;
}

// ---------------- K1: table[v][n] = embed[v] . Wcat[n] + bias[n] ----------------
__global__ __launch_bounds__(256) void k_table_gemm(
    const float* __restrict__ emb, const float* __restrict__ Wf,
    const float* __restrict__ Wb, const float* __restrict__ bf,
    const float* __restrict__ bb, float* __restrict__ table) {
    __shared__ __align__(16) float As[64][68];  // [k][m]
    __shared__ __align__(16) float Bs[64][68];  // [k][n]
    int t  = threadIdx.x;
    int tx = t & 15, ty = t >> 4;
    int n0 = blockIdx.x * 64;
    int v0 = blockIdx.y * 64;
    float acc[4][4] = {};
    for (int kc = 0; kc < 4; ++kc) {
        #pragma unroll
        for (int rr = 0; rr < 4; ++rr) {
            int slot = t + rr * 256;
            int m = slot >> 4, kq = slot & 15;
            int v = v0 + m;
            float4 a = (v < VOCAB)
                ? *(const float4*)&emb[v * EDIM + kc * 64 + kq * 4]
                : make_float4(0.f, 0.f, 0.f, 0.f);
            As[kq * 4 + 0][m] = a.x; As[kq * 4 + 1][m] = a.y;
            As[kq * 4 + 2][m] = a.z; As[kq * 4 + 3][m] = a.w;
            int n = n0 + m;
            const float* Wrow = (n < 1024) ? &Wf[n * 256] : &Wb[(n - 1024) * 256];
            float4 bvec = *(const float4*)&Wrow[kc * 64 + kq * 4];
            Bs[kq * 4 + 0][m] = bvec.x; Bs[kq * 4 + 1][m] = bvec.y;
            Bs[kq * 4 + 2][m] = bvec.z; Bs[kq * 4 + 3][m] = bvec.w;
        }
        __syncthreads();
        #pragma unroll
        for (int k = 0; k < 64; ++k) {
            float4 a = *(const float4*)&As[k][ty * 4];
            float4 b = *(const float4*)&Bs[k][tx * 4];
            acc[0][0] += a.x * b.x; acc[0][1] += a.x * b.y; acc[0][2] += a.x * b.z; acc[0][3] += a.x * b.w;
            acc[1][0] += a.y * b.x; acc[1][1] += a.y * b.y; acc[1][2] += a.y * b.z; acc[1][3] += a.y * b.w;
            acc[2][0] += a.z * b.x; acc[2][1] += a.z * b.y; acc[2][2] += a.z * b.z; acc[2][3] += a.z * b.w;
            acc[3][0] += a.w * b.x; acc[3][1] += a.w * b.y; acc[3][2] += a.w * b.z; acc[3][3] += a.w * b.w;
        }
        __syncthreads();
    }
    int n = n0 + tx * 4;
    const float* bi = (n < 1024) ? &bf[n] : &bb[n - 1024];
    float4 bias = *(const float4*)bi;
    #pragma unroll
    for (int i = 0; i < 4; ++i) {
        int v = v0 + ty * 4 + i;
        if (v < VOCAB) {
            float4 o;
            o.x = acc[i][0] + bias.x; o.y = acc[i][1] + bias.y;
            o.z = acc[i][2] + bias.z; o.w = acc[i][3] + bias.w;
            *(float4*)&table[(size_t)v * 2048 + n] = o;
        }
    }
}

// ---------------- K2: LSTM recurrence ----------------
// 128 blocks: dir = bid>>6, pair = bid&63 -> batches (2p, 2p+1). 512 threads,
// thread t owns gate rows r0=t, r1=512+t.
// W partition per block (1 MB total):
//   k in [0,32)   : LDS-resident (131 KB dynamic, stride-1026 pad).
//   k in [32,96)  : register-resident, 32 named float4, PINNED via opaque asm
//                   so the compiler cannot rematerialize them by reloading
//                   from global every step (round-5: remat => 15 GB FETCH).
//   k in [96,256) : streamed from L2, 2-buffer ping-pong (64 VGPRs in flight).

#define REP16(M) M(0) M(1) M(2) M(3) M(4) M(5) M(6) M(7) M(8) M(9) M(10) M(11) M(12) M(13) M(14) M(15)

#define FMA_F4(WA, WB, H0, H1) \
    a00 += WA.x * H0.x; a01 += WA.x * H1.x; a10 += WB.x * H0.x; a11 += WB.x * H1.x; \
    a00 += WA.y * H0.y; a01 += WA.y * H1.y; a10 += WB.y * H0.y; a11 += WB.y * H1.y; \
    a00 += WA.z * H0.z; a01 += WA.z * H1.z; a10 += WB.z * H0.z; a11 += WB.z * H1.z; \
    a00 += WA.w * H0.w; a01 += WA.w * H1.w; a10 += WB.w * H0.w; a11 += WB.w * H1.w;

#define DECLW(i) float4 wra##i, wrb##i;
#define LOADW(i) wra##i = w0q[8 + (i)]; wrb##i = w1q[8 + (i)];
// Opaque redefinition: makes rematerialization-by-reload illegal; values must
// stay live in VGPRs for the whole kernel.
#define PINW(i) asm volatile("" \
    : "+v"(wra##i.x), "+v"(wra##i.y), "+v"(wra##i.z), "+v"(wra##i.w), \
      "+v"(wrb##i.x), "+v"(wrb##i.y), "+v"(wrb##i.z), "+v"(wrb##i.w));
#define DOTW(i)  { float4 h0 = h40[8 + (i)], h1 = h41[8 + (i)]; FMA_F4(wra##i, wrb##i, h0, h1) }

#define LDG(S, g) \
    S##0 = w0q[24 + 4*(g)]; S##1 = w0q[25 + 4*(g)]; S##2 = w0q[26 + 4*(g)]; S##3 = w0q[27 + 4*(g)]; \
    S##4 = w1q[24 + 4*(g)]; S##5 = w1q[25 + 4*(g)]; S##6 = w1q[26 + 4*(g)]; S##7 = w1q[27 + 4*(g)];

#define FMAG(S, g) { float4 h0, h1; \
    h0 = h40[24 + 4*(g)]; h1 = h41[24 + 4*(g)]; FMA_F4(S##0, S##4, h0, h1) \
    h0 = h40[25 + 4*(g)]; h1 = h41[25 + 4*(g)]; FMA_F4(S##1, S##5, h0, h1) \
    h0 = h40[26 + 4*(g)]; h1 = h41[26 + 4*(g)]; FMA_F4(S##2, S##6, h0, h1) \
    h0 = h40[27 + 4*(g)]; h1 = h41[27 + 4*(g)]; FMA_F4(S##3, S##7, h0, h1) }

#define SHW(k, r) sh_w[(k) * 1026 + (r)]

__global__ __attribute__((amdgpu_flat_work_group_size(512, 512), amdgpu_waves_per_eu(2, 2)))
void k_lstm(
    const int* __restrict__ ids, const float* __restrict__ Whhf,
    const float* __restrict__ Whhb, const float* __restrict__ table,
    const float* __restrict__ Wout, float* __restrict__ emp) {
    extern __shared__ float sh_w[];             // 32 * 1026 floats = 131,328 B
    __shared__ __align__(16) float sh_h[2][HDIM];
    __shared__ float sh_g[2][G4];
    __shared__ float sh_wout[NT][HDIM];
    __shared__ int   sh_ids[2][SEQ];

    int t    = threadIdx.x;
    int bid  = blockIdx.x;
    int dir  = bid >> 6;
    int pair = bid & 63;
    int b0 = pair * 2, b1 = pair * 2 + 1;
    int dirOff = dir * 1024;

    for (int idx = t; idx < 2 * SEQ; idx += 512) {
        int bb = idx >> 9, s = idx & 511;
        sh_ids[bb][s] = ids[(bb ? b1 : b0) * SEQ + s];
    }
    for (int idx = t; idx < NT * HDIM; idx += 512) {
        int tg = idx >> 8, d = idx & 255;
        sh_wout[tg][d] = Wout[tg * (2 * HDIM) + dir * HDIM + d];
    }
    ((float*)sh_h)[t] = 0.f;

    const float* Whh = dir ? Whhb : Whhf;
    // stage k in [0,32) into LDS, transposed [k][row], coalesced global reads
    for (int idx = t; idx < 32 * 1024; idx += 512) {
        int k = idx & 31, r = idx >> 5;
        SHW(k, r) = Whh[(size_t)r * 256 + k];
    }

    int r0 = t, r1 = 512 + t;
    const float4* w0q = (const float4*)(Whh + (size_t)r0 * 256);
    const float4* w1q = (const float4*)(Whh + (size_t)r1 * 256);

    // register-resident weights, k in [32,96), pinned against remat
    REP16(DECLW)
    REP16(LOADW)
    REP16(PINW)

    float c_state = 0.f;
    int ud = t & 255, ub = t >> 8;
    int eg = t >> 4;              // 0..17 valid
    int eb = (eg >= NT) ? 1 : 0;
    int etg = eg - NT * eb;
    int el = t & 15;

    __syncthreads();

    const float4* h40 = (const float4*)sh_h[0];
    const float4* h41 = (const float4*)sh_h[1];

    // prefetch xg for first step
    int s0 = dir ? (SEQ - 1) : 0;
    float xn00, xn01, xn10, xn11;
    {
        const float* tn0 = table + (size_t)sh_ids[0][s0] * 2048 + dirOff;
        const float* tn1 = table + (size_t)sh_ids[1][s0] * 2048 + dirOff;
        xn00 = tn0[r0]; xn01 = tn1[r0]; xn10 = tn0[r1]; xn11 = tn1[r1];
    }

    #pragma unroll 1
    for (int it = 0; it < SEQ; ++it) {
        int s = dir ? (SEQ - 1 - it) : it;
        float a00 = xn00, a01 = xn01, a10 = xn10, a11 = xn11;

        float4 sA0, sA1, sA2, sA3, sA4, sA5, sA6, sA7;
        float4 sB0, sB1, sB2, sB3, sB4, sB5, sB6, sB7;
        LDG(sA, 0)
        LDG(sB, 1)

        // issue next-step xg loads (consumed next iteration)
        {
            int itn = (it + 1 < SEQ) ? it + 1 : it;
            int sn = dir ? (SEQ - 1 - itn) : itn;
            const float* tn0 = table + (size_t)sh_ids[0][sn] * 2048 + dirOff;
            const float* tn1 = table + (size_t)sh_ids[1][sn] * 2048 + dirOff;
            xn00 = tn0[r0]; xn01 = tn1[r0]; xn10 = tn0[r1]; xn11 = tn1[r1];
        }

        // LDS-resident region k in [0,32) (runs while streamed loads fly)
        #pragma unroll
        for (int k = 0; k < 32; ++k) {
            float w0 = SHW(k, r0);
            float w1 = SHW(k, r1);
            float hh0 = sh_h[0][k], hh1 = sh_h[1][k];
            a00 += w0 * hh0; a01 += w0 * hh1;
            a10 += w1 * hh0; a11 += w1 * hh1;
        }

        // register region k in [32,96)
        REP16(DOTW)

        // streamed region k in [96,256): ping-pong
        FMAG(sA, 0)  LDG(sA, 2)
        FMAG(sB, 1)  LDG(sB, 3)
        FMAG(sA, 2)  LDG(sA, 4)
        FMAG(sB, 3)  LDG(sB, 5)
        FMAG(sA, 4)  LDG(sA, 6)
        FMAG(sB, 5)  LDG(sB, 7)
        FMAG(sA, 6)  LDG(sA, 8)
        FMAG(sB, 7)  LDG(sB, 9)
        FMAG(sA, 8)
        FMAG(sB, 9)

        sh_g[0][r0] = a00; sh_g[1][r0] = a01;
        sh_g[0][r1] = a10; sh_g[1][r1] = a11;
        __syncthreads();   // BAR1: gates ready
        {
            float iv = sh_g[ub][ud],       fv = sh_g[ub][256 + ud];
            float gv = sh_g[ub][512 + ud], ov = sh_g[ub][768 + ud];
            float si = 1.f / (1.f + expf(-iv));
            float sf = 1.f / (1.f + expf(-fv));
            float so = 1.f / (1.f + expf(-ov));
            float tg = tanhf(gv);
            c_state = sf * c_state + si * tg;
            sh_h[ub][ud] = so * tanhf(c_state);
        }
        __syncthreads();   // BAR2: new h ready
        if (t < 288) {
            const float* hh = sh_h[eb];
            const float* ww = sh_wout[etg];
            float p = 0.f;
            #pragma unroll
            for (int j = 0; j < 16; ++j) p += hh[el + 16 * j] * ww[el + 16 * j];
            p += __shfl_xor(p, 1);
            p += __shfl_xor(p, 2);
            p += __shfl_xor(p, 4);
            p += __shfl_xor(p, 8);
            if (el == 0) {
                int bglob = eb ? b1 : b0;
                emp[(((size_t)dir * BATCH + bglob) * SEQ + s) * NT + etg] = p;
            }
        }
    }
}

// ---------------- K3: Viterbi decode per batch ----------------
__global__ __launch_bounds__(64) void k_viterbi(
    const float* __restrict__ emp, const float* __restrict__ b_out,
    const float* __restrict__ start_t, const float* __restrict__ end_t,
    const float* __restrict__ trans, const void* __restrict__ maskp,
    const int* __restrict__ mask_is_bool, int* __restrict__ out) {
    __shared__ float sh_em[SEQ][NT];
    __shared__ float sh_score[NT];
    __shared__ float sh_trans[NT * NT];
    __shared__ unsigned char sh_mask[SEQ];
    __shared__ unsigned char sh_hist[SEQ - 1][NT];
    __shared__ unsigned char sh_tags[SEQ];
    int b = blockIdx.x;
    int t = threadIdx.x;
    int isb = *mask_is_bool;
    for (int idx = t; idx < SEQ * NT; idx += 64) {
        int s = idx / NT, tg = idx % NT;
        sh_em[s][tg] = emp[((size_t)b * SEQ + s) * NT + tg]
                     + emp[(((size_t)BATCH + b) * SEQ + s) * NT + tg]
                     + b_out[tg];
    }
    if (isb) {
        const unsigned char* m8 = (const unsigned char*)maskp;
        for (int idx = t; idx < SEQ; idx += 64) sh_mask[idx] = m8[b * SEQ + idx];
    } else {
        const int* m32 = (const int*)maskp;
        for (int idx = t; idx < SEQ; idx += 64) sh_mask[idx] = (unsigned char)(m32[b * SEQ + idx] != 0);
    }
    for (int idx = t; idx < NT * NT; idx += 64) sh_trans[idx] = trans[idx];
    __syncthreads();
    float sc = 0.f;
    if (t < NT) { sc = start_t[t] + sh_em[0][t]; sh_score[t] = sc; }
    __syncthreads();
    for (int s = 1; s < SEQ; ++s) {
        if (t < NT) {
            float m = -3.4e38f; int bp = 0;
            #pragma unroll
            for (int i = 0; i < NT; ++i) {
                float v = sh_score[i] + sh_trans[i * NT + t];
                if (v > m) { m = v; bp = i; }
            }
            sh_hist[s - 1][t] = (unsigned char)bp;
            float best = m + sh_em[s][t];
            if (sh_mask[s]) sc = best;
        }
        __syncthreads();
        if (t < NT) sh_score[t] = sc;
        __syncthreads();
    }
    if (t == 0) {
        float bb = -3.4e38f; int tag = 0;
        for (int j = 0; j < NT; ++j) {
            float v = sh_score[j] + end_t[j];
            if (v > bb) { bb = v; tag = j; }
        }
        for (int pos = SEQ - 1; pos >= 1; --pos) {
            sh_tags[pos] = (unsigned char)tag;
            if (sh_mask[pos]) tag = sh_hist[pos - 1][tag];
        }
        sh_tags[0] = (unsigned char)tag;
    }
    __syncthreads();
    for (int idx = t; idx < SEQ; idx += 64) {
        out[b * SEQ + idx] = sh_mask[idx] ? (int)sh_tags[idx] : 0;
    }
}

extern "C" void kernel_launch(void* const* d_in, const int* in_sizes, int n_in,
                              void* d_out, int out_size, void* d_ws, size_t ws_size,
                              hipStream_t stream) {
    const int*   ids  = (const int*)d_in[0];
    const void*  mask = d_in[1];
    const float* emb  = (const float*)d_in[2];
    const float* Wihf = (const float*)d_in[3];
    const float* Whhf = (const float*)d_in[4];
    const float* bfv  = (const float*)d_in[5];
    const float* Wihb = (const float*)d_in[6];
    const float* Whhb = (const float*)d_in[7];
    const float* bbv  = (const float*)d_in[8];
    const float* Wout = (const float*)d_in[9];
    const float* bout = (const float*)d_in[10];
    const float* st   = (const float*)d_in[11];
    const float* en   = (const float*)d_in[12];
    const float* tr   = (const float*)d_in[13];
    int* out = (int*)d_out;

    char* ws = (char*)d_ws;
    float* table = (float*)ws;                                   // 245,760,000 B
    float* emp   = (float*)(ws + 245760000);                     //   4,718,592 B
    int*   flag  = (int*)(ws + 245760000 + 4718592);             //           4 B

    k_detect<<<1, 128, 0, stream>>>((const unsigned char*)mask, flag);
    dim3 g1(32, 469);
    k_table_gemm<<<g1, 256, 0, stream>>>(emb, Wihf, Wihb, bfv, bbv, table);
    k_lstm<<<128, 512, 32 * 1026 * sizeof(float), stream>>>(ids, Whhf, Whhb, table, Wout, emp);
    k_viterbi<<<128, 64, 0, stream>>>(emp, bout, st, en, tr, mask, flag, out);
}

// Round 7
// 10270.272 us; speedup vs baseline: 1.3198x; 1.3198x over previous
//
#include <hip/hip_runtime.h>
#include <hip/hip_bf16.h>

#define SEQ   512
#define BATCH 128
#define VOCAB 30000
#define EDIM  256
#define HDIM  256
#define G4    1024   // 4*H
#define NT    9

// ---------------- K0b: detect mask storage dtype ----------------
__global__ void k_detect(const unsigned char* __restrict__ m, int* __restrict__ flag) {
    __shared__ int ok_sh;
    if (threadIdx.x == 0) ok_sh = 1;
    __syncthreads();
    int b = threadIdx.x;  // 128 threads, one row each
    const uint4* row = (const uint4*)(m + b * SEQ);
    int ok = 1, prev = 1;
    for (int i = 0; i < SEQ / 16; ++i) {
        uint4 v = row[i];
        unsigned w[4] = {v.x, v.y, v.z, v.w};
        #pragma unroll
        for (int wi = 0; wi < 4; ++wi) {
            #pragma unroll
            for (int j = 0; j < 4; ++j) {
                int byte = (w[wi] >> (8 * j)) & 255;
                if (byte > 1 || byte > prev) ok = 0;
                prev = byte;
            }
        }
    }
    if (!ok) atomicAnd(&ok_sh, 0);
    __syncthreads();
    if (threadIdx.x == 0) *flag = ok_sh;
}

// ---------------- K1: table[v][n] = embed[v] . Wcat[n] + bias[n] ----------------
__global__ __launch_bounds__(256) void k_table_gemm(
    const float* __restrict__ emb, const float* __restrict__ Wf,
    const float* __restrict__ Wb, const float* __restrict__ bf,
    const float* __restrict__ bb, float* __restrict__ table) {
    __shared__ __align__(16) float As[64][68];  // [k][m]
    __shared__ __align__(16) float Bs[64][68];  // [k][n]
    int t  = threadIdx.x;
    int tx = t & 15, ty = t >> 4;
    int n0 = blockIdx.x * 64;
    int v0 = blockIdx.y * 64;
    float acc[4][4] = {};
    for (int kc = 0; kc < 4; ++kc) {
        #pragma unroll
        for (int rr = 0; rr < 4; ++rr) {
            int slot = t + rr * 256;
            int m = slot >> 4, kq = slot & 15;
            int v = v0 + m;
            float4 a = (v < VOCAB)
                ? *(const float4*)&emb[v * EDIM + kc * 64 + kq * 4]
                : make_float4(0.f, 0.f, 0.f, 0.f);
            As[kq * 4 + 0][m] = a.x; As[kq * 4 + 1][m] = a.y;
            As[kq * 4 + 2][m] = a.z; As[kq * 4 + 3][m] = a.w;
            int n = n0 + m;
            const float* Wrow = (n < 1024) ? &Wf[n * 256] : &Wb[(n - 1024) * 256];
            float4 bvec = *(const float4*)&Wrow[kc * 64 + kq * 4];
            Bs[kq * 4 + 0][m] = bvec.x; Bs[kq * 4 + 1][m] = bvec.y;
            Bs[kq * 4 + 2][m] = bvec.z; Bs[kq * 4 + 3][m] = bvec.w;
        }
        __syncthreads();
        #pragma unroll
        for (int k = 0; k < 64; ++k) {
            float4 a = *(const float4*)&As[k][ty * 4];
            float4 b = *(const float4*)&Bs[k][tx * 4];
            acc[0][0] += a.x * b.x; acc[0][1] += a.x * b.y; acc[0][2] += a.x * b.z; acc[0][3] += a.x * b.w;
            acc[1][0] += a.y * b.x; acc[1][1] += a.y * b.y; acc[1][2] += a.y * b.z; acc[1][3] += a.y * b.w;
            acc[2][0] += a.z * b.x; acc[2][1] += a.z * b.y; acc[2][2] += a.z * b.z; acc[2][3] += a.z * b.w;
            acc[3][0] += a.w * b.x; acc[3][1] += a.w * b.y; acc[3][2] += a.w * b.z; acc[3][3] += a.w * b.w;
        }
        __syncthreads();
    }
    int n = n0 + tx * 4;
    const float* bi = (n < 1024) ? &bf[n] : &bb[n - 1024];
    float4 bias = *(const float4*)bi;
    #pragma unroll
    for (int i = 0; i < 4; ++i) {
        int v = v0 + ty * 4 + i;
        if (v < VOCAB) {
            float4 o;
            o.x = acc[i][0] + bias.x; o.y = acc[i][1] + bias.y;
            o.z = acc[i][2] + bias.z; o.w = acc[i][3] + bias.w;
            *(float4*)&table[(size_t)v * 2048 + n] = o;
        }
    }
}

// ---------------- K2: LSTM recurrence ----------------
// 128 blocks. dir = bid & 1, pair = bid >> 1  -- XCD-dir alignment: with the
// observed bid%8 XCD round-robin, every block on a given XCD has the SAME dir,
// so the streamed W working set per XCD-L2 is ~1 MB (one direction) instead of
// 2 MB + drift => W re-reads stay L2-resident (round-6: cross-dir mixing
// thrashed L2 -> 15-21 GB HBM FETCH).
// 512 threads, thread t owns gate rows r0=t, r1=512+t.
// W partition per block (1 MB total):
//   k in [0,32)   : LDS-resident (131 KB dynamic, stride-1026 pad).
//   k in [32,96)  : 32 named float4 (compiler remats from L2 each step).
//   k in [96,256) : streamed from L2, 2-buffer ping-pong.

#define REP16(M) M(0) M(1) M(2) M(3) M(4) M(5) M(6) M(7) M(8) M(9) M(10) M(11) M(12) M(13) M(14) M(15)

#define FMA_F4(WA, WB, H0, H1) \
    a00 += WA.x * H0.x; a01 += WA.x * H1.x; a10 += WB.x * H0.x; a11 += WB.x * H1.x; \
    a00 += WA.y * H0.y; a01 += WA.y * H1.y; a10 += WB.y * H0.y; a11 += WB.y * H1.y; \
    a00 += WA.z * H0.z; a01 += WA.z * H1.z; a10 += WB.z * H0.z; a11 += WB.z * H1.z; \
    a00 += WA.w * H0.w; a01 += WA.w * H1.w; a10 += WB.w * H0.w; a11 += WB.w * H1.w;

#define DECLW(i) float4 wra##i, wrb##i;
#define LOADW(i) wra##i = w0q[8 + (i)]; wrb##i = w1q[8 + (i)];
#define DOTW(i)  { float4 h0 = h40[8 + (i)], h1 = h41[8 + (i)]; FMA_F4(wra##i, wrb##i, h0, h1) }

#define LDG(S, g) \
    S##0 = w0q[24 + 4*(g)]; S##1 = w0q[25 + 4*(g)]; S##2 = w0q[26 + 4*(g)]; S##3 = w0q[27 + 4*(g)]; \
    S##4 = w1q[24 + 4*(g)]; S##5 = w1q[25 + 4*(g)]; S##6 = w1q[26 + 4*(g)]; S##7 = w1q[27 + 4*(g)];

#define FMAG(S, g) { float4 h0, h1; \
    h0 = h40[24 + 4*(g)]; h1 = h41[24 + 4*(g)]; FMA_F4(S##0, S##4, h0, h1) \
    h0 = h40[25 + 4*(g)]; h1 = h41[25 + 4*(g)]; FMA_F4(S##1, S##5, h0, h1) \
    h0 = h40[26 + 4*(g)]; h1 = h41[26 + 4*(g)]; FMA_F4(S##2, S##6, h0, h1) \
    h0 = h40[27 + 4*(g)]; h1 = h41[27 + 4*(g)]; FMA_F4(S##3, S##7, h0, h1) }

#define SHW(k, r) sh_w[(k) * 1026 + (r)]

__global__ __attribute__((amdgpu_flat_work_group_size(512, 512), amdgpu_waves_per_eu(2, 2)))
void k_lstm(
    const int* __restrict__ ids, const float* __restrict__ Whhf,
    const float* __restrict__ Whhb, const float* __restrict__ table,
    const float* __restrict__ Wout, float* __restrict__ emp) {
    extern __shared__ float sh_w[];             // 32 * 1026 floats = 131,328 B
    __shared__ __align__(16) float sh_h[2][HDIM];
    __shared__ float sh_g[2][G4];
    __shared__ float sh_wout[NT][HDIM];
    __shared__ int   sh_ids[2][SEQ];

    int t    = threadIdx.x;
    int bid  = blockIdx.x;
    int dir  = bid & 1;          // XCD-dir alignment (see header comment)
    int pair = bid >> 1;
    int b0 = pair * 2, b1 = pair * 2 + 1;
    int dirOff = dir * 1024;

    for (int idx = t; idx < 2 * SEQ; idx += 512) {
        int bb = idx >> 9, s = idx & 511;
        sh_ids[bb][s] = ids[(bb ? b1 : b0) * SEQ + s];
    }
    for (int idx = t; idx < NT * HDIM; idx += 512) {
        int tg = idx >> 8, d = idx & 255;
        sh_wout[tg][d] = Wout[tg * (2 * HDIM) + dir * HDIM + d];
    }
    ((float*)sh_h)[t] = 0.f;

    const float* Whh = dir ? Whhb : Whhf;
    // stage k in [0,32) into LDS, transposed [k][row], coalesced global reads
    for (int idx = t; idx < 32 * 1024; idx += 512) {
        int k = idx & 31, r = idx >> 5;
        SHW(k, r) = Whh[(size_t)r * 256 + k];
    }

    int r0 = t, r1 = 512 + t;
    const float4* w0q = (const float4*)(Whh + (size_t)r0 * 256);
    const float4* w1q = (const float4*)(Whh + (size_t)r1 * 256);

    // k in [32,96): named float4 (compiler remats from L2 per step; cheap once
    // the W set is L2-resident)
    REP16(DECLW)
    REP16(LOADW)

    float c_state = 0.f;
    int ud = t & 255, ub = t >> 8;
    int eg = t >> 4;              // 0..17 valid
    int eb = (eg >= NT) ? 1 : 0;
    int etg = eg - NT * eb;
    int el = t & 15;

    __syncthreads();

    const float4* h40 = (const float4*)sh_h[0];
    const float4* h41 = (const float4*)sh_h[1];

    // prefetch xg for first step
    int s0 = dir ? (SEQ - 1) : 0;
    float xn00, xn01, xn10, xn11;
    {
        const float* tn0 = table + (size_t)sh_ids[0][s0] * 2048 + dirOff;
        const float* tn1 = table + (size_t)sh_ids[1][s0] * 2048 + dirOff;
        xn00 = tn0[r0]; xn01 = tn1[r0]; xn10 = tn0[r1]; xn11 = tn1[r1];
    }

    #pragma unroll 1
    for (int it = 0; it < SEQ; ++it) {
        int s = dir ? (SEQ - 1 - it) : it;
        float a00 = xn00, a01 = xn01, a10 = xn10, a11 = xn11;

        float4 sA0, sA1, sA2, sA3, sA4, sA5, sA6, sA7;
        float4 sB0, sB1, sB2, sB3, sB4, sB5, sB6, sB7;
        LDG(sA, 0)
        LDG(sB, 1)

        // issue next-step xg loads (consumed next iteration)
        {
            int itn = (it + 1 < SEQ) ? it + 1 : it;
            int sn = dir ? (SEQ - 1 - itn) : itn;
            const float* tn0 = table + (size_t)sh_ids[0][sn] * 2048 + dirOff;
            const float* tn1 = table + (size_t)sh_ids[1][sn] * 2048 + dirOff;
            xn00 = tn0[r0]; xn01 = tn1[r0]; xn10 = tn0[r1]; xn11 = tn1[r1];
        }

        // LDS-resident region k in [0,32) (runs while streamed loads fly)
        #pragma unroll
        for (int k = 0; k < 32; ++k) {
            float w0 = SHW(k, r0);
            float w1 = SHW(k, r1);
            float hh0 = sh_h[0][k], hh1 = sh_h[1][k];
            a00 += w0 * hh0; a01 += w0 * hh1;
            a10 += w1 * hh0; a11 += w1 * hh1;
        }

        // region k in [32,96)
        REP16(DOTW)

        // streamed region k in [96,256): ping-pong
        FMAG(sA, 0)  LDG(sA, 2)
        FMAG(sB, 1)  LDG(sB, 3)
        FMAG(sA, 2)  LDG(sA, 4)
        FMAG(sB, 3)  LDG(sB, 5)
        FMAG(sA, 4)  LDG(sA, 6)
        FMAG(sB, 5)  LDG(sB, 7)
        FMAG(sA, 6)  LDG(sA, 8)
        FMAG(sB, 7)  LDG(sB, 9)
        FMAG(sA, 8)
        FMAG(sB, 9)

        sh_g[0][r0] = a00; sh_g[1][r0] = a01;
        sh_g[0][r1] = a10; sh_g[1][r1] = a11;
        __syncthreads();   // BAR1: gates ready
        {
            float iv = sh_g[ub][ud],       fv = sh_g[ub][256 + ud];
            float gv = sh_g[ub][512 + ud], ov = sh_g[ub][768 + ud];
            float si = 1.f / (1.f + expf(-iv));
            float sf = 1.f / (1.f + expf(-fv));
            float so = 1.f / (1.f + expf(-ov));
            float tg = tanhf(gv);
            c_state = sf * c_state + si * tg;
            sh_h[ub][ud] = so * tanhf(c_state);
        }
        __syncthreads();   // BAR2: new h ready
        if (t < 288) {
            const float* hh = sh_h[eb];
            const float* ww = sh_wout[etg];
            float p = 0.f;
            #pragma unroll
            for (int j = 0; j < 16; ++j) p += hh[el + 16 * j] * ww[el + 16 * j];
            p += __shfl_xor(p, 1);
            p += __shfl_xor(p, 2);
            p += __shfl_xor(p, 4);
            p += __shfl_xor(p, 8);
            if (el == 0) {
                int bglob = eb ? b1 : b0;
                emp[(((size_t)dir * BATCH + bglob) * SEQ + s) * NT + etg] = p;
            }
        }
    }
}

// ---------------- K3: Viterbi decode per batch ----------------
__global__ __launch_bounds__(64) void k_viterbi(
    const float* __restrict__ emp, const float* __restrict__ b_out,
    const float* __restrict__ start_t, const float* __restrict__ end_t,
    const float* __restrict__ trans, const void* __restrict__ maskp,
    const int* __restrict__ mask_is_bool, int* __restrict__ out) {
    __shared__ float sh_em[SEQ][NT];
    __shared__ float sh_score[NT];
    __shared__ float sh_trans[NT * NT];
    __shared__ unsigned char sh_mask[SEQ];
    __shared__ unsigned char sh_hist[SEQ - 1][NT];
    __shared__ unsigned char sh_tags[SEQ];
    int b = blockIdx.x;
    int t = threadIdx.x;
    int isb = *mask_is_bool;
    for (int idx = t; idx < SEQ * NT; idx += 64) {
        int s = idx / NT, tg = idx % NT;
        sh_em[s][tg] = emp[((size_t)b * SEQ + s) * NT + tg]
                     + emp[(((size_t)BATCH + b) * SEQ + s) * NT + tg]
                     + b_out[tg];
    }
    if (isb) {
        const unsigned char* m8 = (const unsigned char*)maskp;
        for (int idx = t; idx < SEQ; idx += 64) sh_mask[idx] = m8[b * SEQ + idx];
    } else {
        const int* m32 = (const int*)maskp;
        for (int idx = t; idx < SEQ; idx += 64) sh_mask[idx] = (unsigned char)(m32[b * SEQ + idx] != 0);
    }
    for (int idx = t; idx < NT * NT; idx += 64) sh_trans[idx] = trans[idx];
    __syncthreads();
    float sc = 0.f;
    if (t < NT) { sc = start_t[t] + sh_em[0][t]; sh_score[t] = sc; }
    __syncthreads();
    for (int s = 1; s < SEQ; ++s) {
        if (t < NT) {
            float m = -3.4e38f; int bp = 0;
            #pragma unroll
            for (int i = 0; i < NT; ++i) {
                float v = sh_score[i] + sh_trans[i * NT + t];
                if (v > m) { m = v; bp = i; }
            }
            sh_hist[s - 1][t] = (unsigned char)bp;
            float best = m + sh_em[s][t];
            if (sh_mask[s]) sc = best;
        }
        __syncthreads();
        if (t < NT) sh_score[t] = sc;
        __syncthreads();
    }
    if (t == 0) {
        float bb = -3.4e38f; int tag = 0;
        for (int j = 0; j < NT; ++j) {
            float v = sh_score[j] + end_t[j];
            if (v > bb) { bb = v; tag = j; }
        }
        for (int pos = SEQ - 1; pos >= 1; --pos) {
            sh_tags[pos] = (unsigned char)tag;
            if (sh_mask[pos]) tag = sh_hist[pos - 1][tag];
        }
        sh_tags[0] = (unsigned char)tag;
    }
    __syncthreads();
    for (int idx = t; idx < SEQ; idx += 64) {
        out[b * SEQ + idx] = sh_mask[idx] ? (int)sh_tags[idx] : 0;
    }
}

extern "C" void kernel_launch(void* const* d_in, const int* in_sizes, int n_in,
                              void* d_out, int out_size, void* d_ws, size_t ws_size,
                              hipStream_t stream) {
    const int*   ids  = (const int*)d_in[0];
    const void*  mask = d_in[1];
    const float* emb  = (const float*)d_in[2];
    const float* Wihf = (const float*)d_in[3];
    const float* Whhf = (const float*)d_in[4];
    const float* bfv  = (const float*)d_in[5];
    const float* Wihb = (const float*)d_in[6];
    const float* Whhb = (const float*)d_in[7];
    const float* bbv  = (const float*)d_in[8];
    const float* Wout = (const float*)d_in[9];
    const float* bout = (const float*)d_in[10];
    const float* st   = (const float*)d_in[11];
    const float* en   = (const float*)d_in[12];
    const float* tr   = (const float*)d_in[13];
    int* out = (int*)d_out;

    char* ws = (char*)d_ws;
    float* table = (float*)ws;                                   // 245,760,000 B
    float* emp   = (float*)(ws + 245760000);                     //   4,718,592 B
    int*   flag  = (int*)(ws + 245760000 + 4718592);             //           4 B

    k_detect<<<1, 128, 0, stream>>>((const unsigned char*)mask, flag);
    dim3 g1(32, 469);
    k_table_gemm<<<g1, 256, 0, stream>>>(emb, Wihf, Wihb, bfv, bbv, table);
    k_lstm<<<128, 512, 32 * 1026 * sizeof(float), stream>>>(ids, Whhf, Whhb, table, Wout, emp);
    k_viterbi<<<128, 64, 0, stream>>>(emp, bout, st, en, tr, mask, flag, out);
}